// Round 3
// baseline (13729.243 us; speedup 1.0000x reference)
//
#include <hip/hip_runtime.h>
#include <hip/hip_bf16.h>
#include <stdint.h>

#define SEQ   512
#define BATCH 2048
#define HID   512
#define XF    31

typedef __bf16 bf16_t;
typedef bf16_t bf16x8 __attribute__((ext_vector_type(8)));
typedef float  f32x4  __attribute__((ext_vector_type(4)));

// async global->LDS, 16B per lane; LDS dest = wave-uniform base + lane*16
__device__ __forceinline__ void gload16(const void* g, void* lds) {
    __builtin_amdgcn_global_load_lds(
        (const __attribute__((address_space(1))) void*)g,
        (__attribute__((address_space(3))) void*)lds,
        16, 0, 0);
}

__device__ __forceinline__ float sigmoid_f(float x) {
    return 1.f / (1.f + __expf(-x));
}
__device__ __forceinline__ float tanh_f(float x) {
    float e = __expf(2.f * x);
    return 1.f - 2.f / (e + 1.f);
}

// ---------------- prologue: weight/state conversion (runs every launch) ----
__global__ void prep_w(const float* __restrict__ W_ih, const float* __restrict__ W_hh,
                       bf16_t* __restrict__ Wcat) {
    const int j = blockIdx.x;                 // 0..2047 (gate row)
    for (int k = threadIdx.x; k < 1024; k += 256) {
        float v = (k < 512) ? W_ih[(size_t)j * 512 + k]
                            : W_hh[(size_t)j * 512 + (k - 512)];
        Wcat[(size_t)j * 1024 + k] = (bf16_t)v;
    }
}

__global__ void prep_state(const float* __restrict__ h0, const float* __restrict__ c0,
                           bf16_t* __restrict__ H0, float* __restrict__ Cbuf) {
    const int b = blockIdx.x;                 // 0..2047
    for (int d = threadIdx.x; d < 512; d += 256) {
        H0[(size_t)b * 512 + d]   = (bf16_t)h0[(size_t)b * 512 + d];
        Cbuf[(size_t)b * 512 + d] = c0[(size_t)b * 512 + d];
    }
}

__global__ void prep_bias(const float* __restrict__ b_ih, const float* __restrict__ b_hh,
                          float* __restrict__ bg) {
    int j = blockIdx.x * 256 + threadIdx.x;
    bg[j] = b_ih[j] + b_hh[j];
}

// ---------------- kernel 1: x0 = relu([x_t, y_prev] @ W_in^T + b_in) -------
// also initializes d_out[t] row to b_out (kernel2 atomically accumulates y)
__global__ __launch_bounds__(256) void input_proj(
    const float* __restrict__ x_t,    // [B][31] slice for this t
    const float* __restrict__ yprev,  // [B] (y0 or d_out slice t-1)
    const float* __restrict__ W_in,   // [512][32]
    const float* __restrict__ b_in,   // [512]
    const float* __restrict__ b_out,  // [1]
    bf16_t* __restrict__ X0,          // [B][512] bf16
    float* __restrict__ yinit)        // d_out + t*B
{
    __shared__ float xs[8][32];
    __shared__ float ys[8];
    const int tid = threadIdx.x;
    const int b0  = blockIdx.x * 8;

    if (tid < 248) {
        int rr = tid / 31, cc = tid % 31;
        xs[rr][cc] = x_t[(size_t)(b0 + rr) * XF + cc];
    } else {
        int rr = tid - 248;
        ys[rr] = yprev[b0 + rr];
        yinit[b0 + rr] = b_out[0];
    }
    __syncthreads();

#pragma unroll
    for (int rep = 0; rep < 2; ++rep) {
        const int hd = tid + rep * 256;       // 0..511
        float wrow[32];
#pragma unroll
        for (int k4 = 0; k4 < 8; ++k4) {
            float4 v = *(const float4*)&W_in[(size_t)hd * 32 + k4 * 4];
            wrow[k4 * 4 + 0] = v.x; wrow[k4 * 4 + 1] = v.y;
            wrow[k4 * 4 + 2] = v.z; wrow[k4 * 4 + 3] = v.w;
        }
        const float bi = b_in[hd];
#pragma unroll
        for (int b = 0; b < 8; ++b) {
            float acc = bi + ys[b] * wrow[31];
#pragma unroll
            for (int k = 0; k < 31; ++k) acc += xs[b][k] * wrow[k];
            acc = fmaxf(acc, 0.f);
            X0[(size_t)(b0 + b) * 512 + hd] = (bf16_t)acc;
        }
    }
}

// ---------------- kernel 2: gates GEMM + fused LSTM cell -------------------
// C[b][n] = sum_k [X0|Hin][b][k] * Wcat[j(n)][k],  j = gate*512 + nb*32 + dl
// 512 threads = 8 waves arranged (2m x 2n x 2k-split) over a 128x128 tile.
// Each wave owns a 64x64 output sub-tile over HALF the BK=64 K-step
// (k-offset wk*32) -> 8 b128 LDS reads per wave per K-step (was 12),
// 64KB/block/K-step total (was 96KB): the K-loop was LDS-read-bound.
// Cross-wk partial sums are reduced in the epilogue through Gs
// (wk=0 writes, wk=1 adds), then the unchanged cell phase runs.
//   - XOR-swizzled LDS tiles (slot s of row holds chunk s^(row&7)), staged
//     via pre-swizzled global source, read with the same XOR. Conflict-free.
//   - 2-buffer pipeline: stage kt+1 before compute kt; one vmcnt(0)+barrier
//     per K-step.
__global__ __launch_bounds__(512, 1) void step_gemm_cell(
    const bf16_t* __restrict__ X0,    // [B][512]
    const bf16_t* __restrict__ Hin,   // [B][512]
    bf16_t* __restrict__ Hout,        // [B][512]
    float*  __restrict__ Cbuf,        // [B][512] fp32
    const bf16_t* __restrict__ Wcat,  // [2048][1024]
    const float*  __restrict__ b_gate,// [2048]
    const float*  __restrict__ W_out, // [512]
    float*  __restrict__ yout)        // d_out + t*B (pre-set to b_out)
{
    __shared__ __align__(16) char smem[65536];
    typedef bf16_t Tile[128][64];
    Tile* As = (Tile*)smem;                    // As[0],As[1]: 32 KiB
    Tile* Bs = (Tile*)(smem + 32768);          // Bs[0],Bs[1]: 32 KiB
    float (*Gs)[128] = (float (*)[128])smem;   // overlay (valid after K-loop)

    const int tid  = threadIdx.x;
    const int lane = tid & 63;
    const int wid  = tid >> 6;        // 0..7
    const int wm   = wid >> 2;        // 0..1 (m half: 64 rows)
    const int wn   = (wid >> 1) & 1;  // 0..1 (n half: 64 cols)
    const int wk   = wid & 1;         // 0..1 (k half of BK=64)
    const int nb   = blockIdx.x;      // 0..15 -> d in [nb*32, nb*32+32)
    const int mb   = blockIdx.y;      // 0..15 -> b in [mb*128, ...)

    const int r  = lane & 15, q = lane >> 4;
    const int lr  = lane >> 3;        // row-in-8 for the staging loads
    const int lcs = ((lane & 7) ^ lr) * 8;       // swizzled SOURCE k-chunk
    const int ko  = (((wk << 2) + q) ^ (r & 7)) << 3; // swizzled read col (elems)

    f32x4 acc[4][4];
#pragma unroll
    for (int mi = 0; mi < 4; ++mi)
#pragma unroll
        for (int ni = 0; ni < 4; ++ni) {
            f32x4 z = {0.f, 0.f, 0.f, 0.f};
            acc[mi][ni] = z;
        }

    // stage K-step kt into buffer dst (4 gload16 per thread = 32 KiB/block)
    auto stage = [&](int dst, int kt) {
        const bf16_t* abase = (kt < 8) ? X0 : Hin;
        const int k0 = (kt & 7) * 64;
#pragma unroll
        for (int iss = 0; iss < 2; ++iss) {
            const int r0 = wid * 16 + iss * 8;       // r0 % 8 == 0
            gload16(abase + (size_t)(mb * 128 + r0 + lr) * 512 + k0 + lcs,
                    &As[dst][r0][0]);
        }
#pragma unroll
        for (int iss = 0; iss < 2; ++iss) {
            const int r0   = wid * 16 + iss * 8;
            const int nloc = r0 + lr;
            const int j    = (nloc >> 5) * 512 + nb * 32 + (nloc & 31);
            gload16(Wcat + (size_t)j * 1024 + kt * 64 + lcs,
                    &Bs[dst][r0][0]);
        }
    };

    // prologue: fill buffer 0
    stage(0, 0);
    asm volatile("s_waitcnt vmcnt(0)" ::: "memory");
    __builtin_amdgcn_s_barrier();

    int cur = 0;
    for (int kt = 0; kt < 16; ++kt) {
        if (kt < 15) stage(cur ^ 1, kt + 1);   // prefetch next K-step
        bf16x8 af[4], bfr[4];
#pragma unroll
        for (int mi = 0; mi < 4; ++mi)
            af[mi] = *(const bf16x8*)&As[cur][wm * 64 + mi * 16 + r][ko];
#pragma unroll
        for (int ni = 0; ni < 4; ++ni)
            bfr[ni] = *(const bf16x8*)&Bs[cur][wn * 64 + ni * 16 + r][ko];
#pragma unroll
        for (int mi = 0; mi < 4; ++mi)
#pragma unroll
            for (int ni = 0; ni < 4; ++ni)
                acc[mi][ni] = __builtin_amdgcn_mfma_f32_16x16x32_bf16(
                    af[mi], bfr[ni], acc[mi][ni], 0, 0, 0);
        // next buffer's loads landed; all waves done reading cur
        asm volatile("s_waitcnt vmcnt(0)" ::: "memory");
        __builtin_amdgcn_s_barrier();
        cur ^= 1;
    }

    // ---- epilogue ----
    const int row = tid >> 3;             // 0..63
    const int oct = tid & 7;              // 0..7

    // prefetch cell state (latency hides under the Gs phases)
    float cv[2][4];
#pragma unroll
    for (int h = 0; h < 2; ++h)
#pragma unroll
        for (int ii = 0; ii < 4; ++ii)
            cv[h][ii] = Cbuf[(size_t)(mb * 128 + h * 64 + row) * 512
                             + nb * 32 + oct * 4 + ii];

    // two m-halves through Gs (C layout: col=lane&15, row=q*4+reg)
#pragma unroll
    for (int h = 0; h < 2; ++h) {
        if (wm == h && wk == 0) {
#pragma unroll
            for (int mi = 0; mi < 4; ++mi)
#pragma unroll
                for (int ni = 0; ni < 4; ++ni)
#pragma unroll
                    for (int rr = 0; rr < 4; ++rr)
                        Gs[mi * 16 + q * 4 + rr][wn * 64 + ni * 16 + r] = acc[mi][ni][rr];
        }
        __syncthreads();
        if (wm == h && wk == 1) {
#pragma unroll
            for (int mi = 0; mi < 4; ++mi)
#pragma unroll
                for (int ni = 0; ni < 4; ++ni)
#pragma unroll
                    for (int rr = 0; rr < 4; ++rr)
                        Gs[mi * 16 + q * 4 + rr][wn * 64 + ni * 16 + r] += acc[mi][ni][rr];
        }
        __syncthreads();
        {
            const int b_glob = mb * 128 + h * 64 + row;
            float yp = 0.f;
#pragma unroll
            for (int ii = 0; ii < 4; ++ii) {
                const int dl     = oct * 4 + ii;    // 0..31
                const int d_glob = nb * 32 + dl;
                float gi = Gs[row][dl]      + b_gate[d_glob];
                float gf = Gs[row][32 + dl] + b_gate[512  + d_glob];
                float gg = Gs[row][64 + dl] + b_gate[1024 + d_glob];
                float go = Gs[row][96 + dl] + b_gate[1536 + d_glob];
                float is = sigmoid_f(gi);
                float fs = sigmoid_f(gf);
                float os = sigmoid_f(go);
                float gt = tanh_f(gg);
                const size_t idx = (size_t)b_glob * 512 + d_glob;
                float c_new = fs * cv[h][ii] + is * gt;
                float hval  = os * tanh_f(c_new);
                Cbuf[idx] = c_new;
                Hout[idx] = (bf16_t)hval;
                yp += hval * W_out[d_glob];
            }
            yp += __shfl_xor(yp, 1);
            yp += __shfl_xor(yp, 2);
            yp += __shfl_xor(yp, 4);
            if (oct == 0) atomicAdd(&yout[b_glob], yp);
        }
        __syncthreads();
    }
}

// ---------------------------------------------------------------------------
extern "C" void kernel_launch(void* const* d_in, const int* in_sizes, int n_in,
                              void* d_out, int out_size, void* d_ws, size_t ws_size,
                              hipStream_t stream) {
    const float* x     = (const float*)d_in[0];
    const float* h0    = (const float*)d_in[1];
    const float* c0    = (const float*)d_in[2];
    const float* y0    = (const float*)d_in[3];
    const float* W_in  = (const float*)d_in[4];
    const float* b_in  = (const float*)d_in[5];
    const float* W_ih  = (const float*)d_in[6];
    const float* W_hh  = (const float*)d_in[7];
    const float* b_ih  = (const float*)d_in[8];
    const float* b_hh  = (const float*)d_in[9];
    const float* W_out = (const float*)d_in[10];
    const float* b_out = (const float*)d_in[11];
    float* out = (float*)d_out;

    char* ws = (char*)d_ws;
    bf16_t* Wcat  = (bf16_t*)(ws);                 // 4 MiB  [2048][1024] bf16
    bf16_t* X0    = (bf16_t*)(ws + (4u << 20));    // 2 MiB  [2048][512]  bf16
    bf16_t* Hb0   = (bf16_t*)(ws + (6u << 20));    // 2 MiB
    bf16_t* Hb1   = (bf16_t*)(ws + (8u << 20));    // 2 MiB
    float*  Cbuf  = (float*)(ws + (10u << 20));    // 4 MiB  [2048][512]  f32
    float*  bgate = (float*)(ws + (14u << 20));    // 8 KiB  [2048]       f32
    bf16_t* Hb[2] = { Hb0, Hb1 };

    prep_w    <<<2048, 256, 0, stream>>>(W_ih, W_hh, Wcat);
    prep_state<<<2048, 256, 0, stream>>>(h0, c0, Hb[0], Cbuf);
    prep_bias <<<8,    256, 0, stream>>>(b_ih, b_hh, bgate);

    for (int t = 0; t < SEQ; ++t) {
        const float* yprev = (t == 0) ? y0 : (out + (size_t)(t - 1) * BATCH);
        input_proj<<<256, 256, 0, stream>>>(
            x + (size_t)t * BATCH * XF, yprev, W_in, b_in, b_out,
            X0, out + (size_t)t * BATCH);
        step_gemm_cell<<<dim3(16, 16), 512, 0, stream>>>(
            X0, Hb[t & 1], Hb[(t + 1) & 1], Cbuf, Wcat, bgate, W_out,
            out + (size_t)t * BATCH);
    }
    (void)in_sizes; (void)n_in; (void)out_size; (void)ws_size;
}

// Round 4
// 12348.228 us; speedup vs baseline: 1.1118x; 1.1118x over previous
//
#include <hip/hip_runtime.h>
#include <hip/hip_bf16.h>
#include <stdint.h>

#define SEQ   512
#define BATCH 2048
#define HID   512
#define XF    31

typedef __bf16 bf16_t;
typedef bf16_t bf16x8 __attribute__((ext_vector_type(8)));
typedef float  f32x4  __attribute__((ext_vector_type(4)));

// async global->LDS, 16B per lane; LDS dest = wave-uniform base + lane*16
__device__ __forceinline__ void gload16(const void* g, void* lds) {
    __builtin_amdgcn_global_load_lds(
        (const __attribute__((address_space(1))) void*)g,
        (__attribute__((address_space(3))) void*)lds,
        16, 0, 0);
}

__device__ __forceinline__ float sigmoid_f(float x) {
    return 1.f / (1.f + __expf(-x));
}
__device__ __forceinline__ float tanh_f(float x) {
    float e = __expf(2.f * x);
    return 1.f - 2.f / (e + 1.f);
}

// ---------------- prologue: weight/state conversion (runs every launch) ----
__global__ void prep_w(const float* __restrict__ W_ih, const float* __restrict__ W_hh,
                       bf16_t* __restrict__ Wcat) {
    const int j = blockIdx.x;                 // 0..2047 (gate row)
    for (int k = threadIdx.x; k < 1024; k += 256) {
        float v = (k < 512) ? W_ih[(size_t)j * 512 + k]
                            : W_hh[(size_t)j * 512 + (k - 512)];
        Wcat[(size_t)j * 1024 + k] = (bf16_t)v;
    }
}

__global__ void prep_state(const float* __restrict__ h0, const float* __restrict__ c0,
                           bf16_t* __restrict__ H0, float* __restrict__ Cbuf) {
    const int b = blockIdx.x;                 // 0..2047
    for (int d = threadIdx.x; d < 512; d += 256) {
        H0[(size_t)b * 512 + d]   = (bf16_t)h0[(size_t)b * 512 + d];
        Cbuf[(size_t)b * 512 + d] = c0[(size_t)b * 512 + d];
    }
}

__global__ void prep_bias(const float* __restrict__ b_ih, const float* __restrict__ b_hh,
                          float* __restrict__ bg) {
    int j = blockIdx.x * 256 + threadIdx.x;
    bg[j] = b_ih[j] + b_hh[j];
}

// ---------------- kernel 1: x0 = relu([x_t, y_prev] @ W_in^T + b_in) -------
__global__ __launch_bounds__(256) void input_proj(
    const float* __restrict__ x_t,    // [B][31] slice for this t
    const float* __restrict__ yprev,  // [B] (y0 or d_out slice t-1)
    const float* __restrict__ W_in,   // [512][32]
    const float* __restrict__ b_in,   // [512]
    const float* __restrict__ b_out,  // [1]
    bf16_t* __restrict__ X0,          // [B][512] bf16
    float* __restrict__ yinit)        // d_out + t*B
{
    __shared__ float xs[8][32];
    __shared__ float ys[8];
    const int tid = threadIdx.x;
    const int b0  = blockIdx.x * 8;

    if (tid < 248) {
        int rr = tid / 31, cc = tid % 31;
        xs[rr][cc] = x_t[(size_t)(b0 + rr) * XF + cc];
    } else {
        int rr = tid - 248;
        ys[rr] = yprev[b0 + rr];
        yinit[b0 + rr] = b_out[0];
    }
    __syncthreads();

#pragma unroll
    for (int rep = 0; rep < 2; ++rep) {
        const int hd = tid + rep * 256;       // 0..511
        float wrow[32];
#pragma unroll
        for (int k4 = 0; k4 < 8; ++k4) {
            float4 v = *(const float4*)&W_in[(size_t)hd * 32 + k4 * 4];
            wrow[k4 * 4 + 0] = v.x; wrow[k4 * 4 + 1] = v.y;
            wrow[k4 * 4 + 2] = v.z; wrow[k4 * 4 + 3] = v.w;
        }
        const float bi = b_in[hd];
#pragma unroll
        for (int b = 0; b < 8; ++b) {
            float acc = bi + ys[b] * wrow[31];
#pragma unroll
            for (int k = 0; k < 31; ++k) acc += xs[b][k] * wrow[k];
            acc = fmaxf(acc, 0.f);
            X0[(size_t)(b0 + b) * 512 + hd] = (bf16_t)acc;
        }
    }
}

// ---------------- kernel 2: gates GEMM + fused LSTM cell -------------------
// C[b][n] = sum_k [X0|Hin][b][k] * Wcat[j(n)][k],  j = gate*512 + nb*32 + dl
// 512 threads = 8 waves (2m x 2n x 2k-split), 128x128 tile, BK=64, 16 K-steps.
// NEW: depth-2 counted-vmcnt pipeline (T3/T4):
//   - 4 LDS buffers (As[4]+Bs[4] = 128 KiB); iter kt stages kt+2, then waits
//     vmcnt(8) (retires the loads for buffer kt&3, issued 2 iters ago),
//     ONE s_barrier + sched_barrier(0), then ds_read+MFMA. No drain-to-0
//     in the main loop (tail peels 8->4->0).
//   - overwrite-safety: buffer (kt+2)&3 was last read before barrier(kt-1),
//     which every wave has passed before any wave can stage at iter kt.
//   - epilogue: both k-halves write in parallel to Gs0/Gs1 overlays (one
//     sync), cell reads Gs0+Gs1 with XOR col-swizzle (bank-conflict-free).
__global__ __launch_bounds__(512, 1) void step_gemm_cell(
    const bf16_t* __restrict__ X0,    // [B][512]
    const bf16_t* __restrict__ Hin,   // [B][512]
    bf16_t* __restrict__ Hout,        // [B][512]
    float*  __restrict__ Cbuf,        // [B][512] fp32
    const bf16_t* __restrict__ Wcat,  // [2048][1024]
    const float*  __restrict__ b_gate,// [2048]
    const float*  __restrict__ W_out, // [512]
    float*  __restrict__ yout)        // d_out + t*B (pre-set to b_out)
{
    __shared__ __align__(16) char smem[131072];
    typedef bf16_t Tile[128][64];
    Tile* As = (Tile*)smem;                       // 4 x 16 KiB
    Tile* Bs = (Tile*)(smem + 65536);             // 4 x 16 KiB
    float (*Gs0)[128] = (float (*)[128])smem;             // overlay [0,64K)
    float (*Gs1)[128] = (float (*)[128])(smem + 65536);   // overlay [64K,128K)

    const int tid  = threadIdx.x;
    const int lane = tid & 63;
    const int wid  = tid >> 6;        // 0..7
    const int wm   = wid >> 2;        // 0..1 (m half: 64 rows)
    const int wn   = (wid >> 1) & 1;  // 0..1 (n half: 64 cols)
    const int wk   = wid & 1;         // 0..1 (k half of BK=64)
    const int nb   = blockIdx.x;      // 0..15 -> d in [nb*32, nb*32+32)
    const int mb   = blockIdx.y;      // 0..15 -> b in [mb*128, ...)

    const int r  = lane & 15, q = lane >> 4;
    const int lr  = lane >> 3;        // row-in-8 for the staging loads
    const int lcs = ((lane & 7) ^ lr) * 8;            // swizzled SOURCE k-chunk
    const int ko  = (((wk << 2) + q) ^ (r & 7)) << 3; // swizzled read col (elems)

    f32x4 acc[4][4];
#pragma unroll
    for (int mi = 0; mi < 4; ++mi)
#pragma unroll
        for (int ni = 0; ni < 4; ++ni) {
            f32x4 z = {0.f, 0.f, 0.f, 0.f};
            acc[mi][ni] = z;
        }

    // stage K-step kt into buffer dst (4 gload16 per thread = 32 KiB/block)
    auto stage = [&](int dst, int kt) {
        const bf16_t* abase = (kt < 8) ? X0 : Hin;
        const int k0 = (kt & 7) * 64;
#pragma unroll
        for (int iss = 0; iss < 2; ++iss) {
            const int r0 = wid * 16 + iss * 8;       // r0 % 8 == 0
            gload16(abase + (size_t)(mb * 128 + r0 + lr) * 512 + k0 + lcs,
                    &As[dst][r0][0]);
        }
#pragma unroll
        for (int iss = 0; iss < 2; ++iss) {
            const int r0   = wid * 16 + iss * 8;
            const int nloc = r0 + lr;
            const int j    = (nloc >> 5) * 512 + nb * 32 + (nloc & 31);
            gload16(Wcat + (size_t)j * 1024 + kt * 64 + lcs,
                    &Bs[dst][r0][0]);
        }
    };

    // prologue: buffers 0,1 in flight (8 loads/thread)
    stage(0, 0);
    stage(1, 1);

#pragma unroll
    for (int kt = 0; kt < 16; ++kt) {
        if (kt + 2 < 16) stage((kt + 2) & 3, kt + 2);
        if (kt < 14) {
            asm volatile("s_waitcnt vmcnt(8)" ::: "memory");
        } else if (kt == 14) {
            asm volatile("s_waitcnt vmcnt(4)" ::: "memory");
        } else {
            asm volatile("s_waitcnt vmcnt(0)" ::: "memory");
        }
        __builtin_amdgcn_s_barrier();
        __builtin_amdgcn_sched_barrier(0);

        const int cur = kt & 3;
        bf16x8 af[4], bfr[4];
#pragma unroll
        for (int mi = 0; mi < 4; ++mi)
            af[mi] = *(const bf16x8*)&As[cur][wm * 64 + mi * 16 + r][ko];
#pragma unroll
        for (int ni = 0; ni < 4; ++ni)
            bfr[ni] = *(const bf16x8*)&Bs[cur][wn * 64 + ni * 16 + r][ko];
#pragma unroll
        for (int mi = 0; mi < 4; ++mi)
#pragma unroll
            for (int ni = 0; ni < 4; ++ni)
                acc[mi][ni] = __builtin_amdgcn_mfma_f32_16x16x32_bf16(
                    af[mi], bfr[ni], acc[mi][ni], 0, 0, 0);
    }

    // ---- epilogue ----
    const int row    = tid >> 2;          // 0..127
    const int dq     = (tid & 3) * 8;     // 0..24 (8 d's per thread)
    const int b_glob = mb * 128 + row;

    // prefetch cell state + W_out (latency hides under the Gs phase)
    float cv[8], wo[8];
    *(float4*)&cv[0] = *(const float4*)&Cbuf[(size_t)b_glob * 512 + nb * 32 + dq];
    *(float4*)&cv[4] = *(const float4*)&Cbuf[(size_t)b_glob * 512 + nb * 32 + dq + 4];
    *(float4*)&wo[0] = *(const float4*)&W_out[nb * 32 + dq];
    *(float4*)&wo[4] = *(const float4*)&W_out[nb * 32 + dq + 4];

    __syncthreads();   // all MFMA reads done -> overlay Gs on staging LDS

    // both k-halves store in parallel; XOR col-swizzle kills bank conflicts
    {
        float (*G)[128] = wk ? Gs1 : Gs0;
#pragma unroll
        for (int mi = 0; mi < 4; ++mi)
#pragma unroll
            for (int ni = 0; ni < 4; ++ni)
#pragma unroll
                for (int rr = 0; rr < 4; ++rr) {
                    const int gr = wm * 64 + mi * 16 + q * 4 + rr;
                    const int gc = wn * 64 + ni * 16 + r;
                    G[gr][gc ^ ((gr & 7) << 2)] = acc[mi][ni][rr];
                }
    }
    __syncthreads();

    {
        const int sx = (row & 7) << 2;
        float cnew[8];
        bf16_t hv[8];
        float yp = 0.f;
#pragma unroll
        for (int ii = 0; ii < 8; ++ii) {
            const int dl     = dq + ii;         // 0..31
            const int d_glob = nb * 32 + dl;
            const int c0x = (dl)      ^ sx;
            const int c1x = (32 + dl) ^ sx;
            const int c2x = (64 + dl) ^ sx;
            const int c3x = (96 + dl) ^ sx;
            float gi = Gs0[row][c0x] + Gs1[row][c0x] + b_gate[d_glob];
            float gf = Gs0[row][c1x] + Gs1[row][c1x] + b_gate[512  + d_glob];
            float gg = Gs0[row][c2x] + Gs1[row][c2x] + b_gate[1024 + d_glob];
            float go = Gs0[row][c3x] + Gs1[row][c3x] + b_gate[1536 + d_glob];
            float is = sigmoid_f(gi);
            float fs = sigmoid_f(gf);
            float os = sigmoid_f(go);
            float gt = tanh_f(gg);
            float c_new = fs * cv[ii] + is * gt;
            float hval  = os * tanh_f(c_new);
            cnew[ii] = c_new;
            hv[ii]   = (bf16_t)hval;
            yp += hval * wo[ii];
        }
        const size_t base = (size_t)b_glob * 512 + nb * 32 + dq;
        *(float4*)&Cbuf[base]     = *(const float4*)&cnew[0];
        *(float4*)&Cbuf[base + 4] = *(const float4*)&cnew[4];
        *(bf16x8*)&Hout[base]     = *(const bf16x8*)&hv[0];

        yp += __shfl_xor(yp, 1);
        yp += __shfl_xor(yp, 2);
        if ((tid & 3) == 0) atomicAdd(&yout[b_glob], yp);
    }
}

// ---------------------------------------------------------------------------
extern "C" void kernel_launch(void* const* d_in, const int* in_sizes, int n_in,
                              void* d_out, int out_size, void* d_ws, size_t ws_size,
                              hipStream_t stream) {
    const float* x     = (const float*)d_in[0];
    const float* h0    = (const float*)d_in[1];
    const float* c0    = (const float*)d_in[2];
    const float* y0    = (const float*)d_in[3];
    const float* W_in  = (const float*)d_in[4];
    const float* b_in  = (const float*)d_in[5];
    const float* W_ih  = (const float*)d_in[6];
    const float* W_hh  = (const float*)d_in[7];
    const float* b_ih  = (const float*)d_in[8];
    const float* b_hh  = (const float*)d_in[9];
    const float* W_out = (const float*)d_in[10];
    const float* b_out = (const float*)d_in[11];
    float* out = (float*)d_out;

    char* ws = (char*)d_ws;
    bf16_t* Wcat  = (bf16_t*)(ws);                 // 4 MiB  [2048][1024] bf16
    bf16_t* X0    = (bf16_t*)(ws + (4u << 20));    // 2 MiB  [2048][512]  bf16
    bf16_t* Hb0   = (bf16_t*)(ws + (6u << 20));    // 2 MiB
    bf16_t* Hb1   = (bf16_t*)(ws + (8u << 20));    // 2 MiB
    float*  Cbuf  = (float*)(ws + (10u << 20));    // 4 MiB  [2048][512]  f32
    float*  bgate = (float*)(ws + (14u << 20));    // 8 KiB  [2048]       f32
    bf16_t* Hb[2] = { Hb0, Hb1 };

    prep_w    <<<2048, 256, 0, stream>>>(W_ih, W_hh, Wcat);
    prep_state<<<2048, 256, 0, stream>>>(h0, c0, Hb[0], Cbuf);
    prep_bias <<<8,    256, 0, stream>>>(b_ih, b_hh, bgate);

    for (int t = 0; t < SEQ; ++t) {
        const float* yprev = (t == 0) ? y0 : (out + (size_t)(t - 1) * BATCH);
        input_proj<<<256, 256, 0, stream>>>(
            x + (size_t)t * BATCH * XF, yprev, W_in, b_in, b_out,
            X0, out + (size_t)t * BATCH);
        step_gemm_cell<<<dim3(16, 16), 512, 0, stream>>>(
            X0, Hb[t & 1], Hb[(t + 1) & 1], Cbuf, Wcat, bgate, W_out,
            out + (size_t)t * BATCH);
    }
    (void)in_sizes; (void)n_in; (void)out_size; (void)ws_size;
}

// Round 5
// 11541.010 us; speedup vs baseline: 1.1896x; 1.0699x over previous
//
#include <hip/hip_runtime.h>
#include <hip/hip_bf16.h>
#include <stdint.h>

#define SEQ   512
#define BATCH 2048
#define HID   512
#define XF    31

typedef __bf16 bf16_t;
typedef bf16_t bf16x8 __attribute__((ext_vector_type(8)));
typedef float  f32x4  __attribute__((ext_vector_type(4)));

// async global->LDS, 16B per lane; LDS dest = wave-uniform base + lane*16
__device__ __forceinline__ void gload16(const void* g, void* lds) {
    __builtin_amdgcn_global_load_lds(
        (const __attribute__((address_space(1))) void*)g,
        (__attribute__((address_space(3))) void*)lds,
        16, 0, 0);
}

__device__ __forceinline__ float sigmoid_f(float x) {
    return 1.f / (1.f + __expf(-x));
}
__device__ __forceinline__ float tanh_f(float x) {
    float e = __expf(2.f * x);
    return 1.f - 2.f / (e + 1.f);
}

// ---------------- prologue: weight/state conversion (runs every launch) ----
__global__ void prep_w(const float* __restrict__ W_ih, const float* __restrict__ W_hh,
                       bf16_t* __restrict__ Wcat) {
    const int j = blockIdx.x;                 // 0..2047 (gate row)
    for (int k = threadIdx.x; k < 1024; k += 256) {
        float v = (k < 512) ? W_ih[(size_t)j * 512 + k]
                            : W_hh[(size_t)j * 512 + (k - 512)];
        Wcat[(size_t)j * 1024 + k] = (bf16_t)v;
    }
}

__global__ void prep_state(const float* __restrict__ h0, const float* __restrict__ c0,
                           bf16_t* __restrict__ H0, float* __restrict__ Cbuf) {
    const int b = blockIdx.x;                 // 0..2047
    for (int d = threadIdx.x; d < 512; d += 256) {
        H0[(size_t)b * 512 + d]   = (bf16_t)h0[(size_t)b * 512 + d];
        Cbuf[(size_t)b * 512 + d] = c0[(size_t)b * 512 + d];
    }
}

__global__ void prep_bias(const float* __restrict__ b_ih, const float* __restrict__ b_hh,
                          float* __restrict__ bg) {
    int j = blockIdx.x * 256 + threadIdx.x;
    bg[j] = b_ih[j] + b_hh[j];
}

// ---------------- kernel 1: x0 = relu([x_t, y_prev] @ W_in^T + b_in) -------
__global__ __launch_bounds__(256) void input_proj(
    const float* __restrict__ x_t,    // [B][31] slice for this t
    const float* __restrict__ yprev,  // [B] (y0 or d_out slice t-1)
    const float* __restrict__ W_in,   // [512][32]
    const float* __restrict__ b_in,   // [512]
    const float* __restrict__ b_out,  // [1]
    bf16_t* __restrict__ X0,          // [B][512] bf16
    float* __restrict__ yinit)        // d_out + t*B
{
    __shared__ float xs[8][32];
    __shared__ float ys[8];
    const int tid = threadIdx.x;
    const int b0  = blockIdx.x * 8;

    if (tid < 248) {
        int rr = tid / 31, cc = tid % 31;
        xs[rr][cc] = x_t[(size_t)(b0 + rr) * XF + cc];
    } else {
        int rr = tid - 248;
        ys[rr] = yprev[b0 + rr];
        yinit[b0 + rr] = b_out[0];
    }
    __syncthreads();

#pragma unroll
    for (int rep = 0; rep < 2; ++rep) {
        const int hd = tid + rep * 256;       // 0..511
        float wrow[32];
#pragma unroll
        for (int k4 = 0; k4 < 8; ++k4) {
            float4 v = *(const float4*)&W_in[(size_t)hd * 32 + k4 * 4];
            wrow[k4 * 4 + 0] = v.x; wrow[k4 * 4 + 1] = v.y;
            wrow[k4 * 4 + 2] = v.z; wrow[k4 * 4 + 3] = v.w;
        }
        const float bi = b_in[hd];
#pragma unroll
        for (int b = 0; b < 8; ++b) {
            float acc = bi + ys[b] * wrow[31];
#pragma unroll
            for (int k = 0; k < 31; ++k) acc += xs[b][k] * wrow[k];
            acc = fmaxf(acc, 0.f);
            X0[(size_t)(b0 + b) * 512 + hd] = (bf16_t)acc;
        }
    }
}

// ---------------- kernel 2: gates GEMM + fused LSTM cell -------------------
// C[b][n] = sum_k [X0|Hin][b][k] * Wcat[j(n)][k],  j = gate*512 + nb*32 + dl
// 512 threads = 8 waves (2m x 2n x 2k-split), 128x128 tile, BK=64, 16 K-steps.
// Depth-2 counted-vmcnt pipeline (4 LDS buffers, vmcnt(8)/4/0 tail), XOR-
// swizzled tiles, parallel Gs0/Gs1 k-reduce epilogue — unchanged from R4.
// NEW (R5): XCD-aware 1-D grid remap. Assuming round-robin dispatch
// (XCD = blockIdx.x % 8, measured m09-style), tile the (mb,nb) space as a
// 4x2 XCD rectangle: each XCD owns 4 mb x 8 nb. Effects:
//   - A (X0/Hin) slices pulled through L3 by 2 XCDs instead of 8 (-4x)
//   - mapping stable across the 512 launches -> each XCD's Wcat slice
//     (2 MB), Cbuf slice and Hout slice stay L2-resident step-to-step.
// If the dispatch assumption is wrong this degrades to the old arbitrary
// mapping (perf-neutral, never incorrect).
__global__ __launch_bounds__(512, 1) void step_gemm_cell(
    const bf16_t* __restrict__ X0,    // [B][512]
    const bf16_t* __restrict__ Hin,   // [B][512]
    bf16_t* __restrict__ Hout,        // [B][512]
    float*  __restrict__ Cbuf,        // [B][512] fp32
    const bf16_t* __restrict__ Wcat,  // [2048][1024]
    const float*  __restrict__ b_gate,// [2048]
    const float*  __restrict__ W_out, // [512]
    float*  __restrict__ yout)        // d_out + t*B (pre-set to b_out)
{
    __shared__ __align__(16) char smem[131072];
    typedef bf16_t Tile[128][64];
    Tile* As = (Tile*)smem;                       // 4 x 16 KiB
    Tile* Bs = (Tile*)(smem + 65536);             // 4 x 16 KiB
    float (*Gs0)[128] = (float (*)[128])smem;             // overlay [0,64K)
    float (*Gs1)[128] = (float (*)[128])(smem + 65536);   // overlay [64K,128K)

    const int tid  = threadIdx.x;
    const int lane = tid & 63;
    const int wid  = tid >> 6;        // 0..7
    const int wm   = wid >> 2;        // 0..1 (m half: 64 rows)
    const int wn   = (wid >> 1) & 1;  // 0..1 (n half: 64 cols)
    const int wk   = wid & 1;         // 0..1 (k half of BK=64)

    // XCD-stable decode: bid = xcd + 8*slot; XCD (xm,xn) on a 4x2 grid
    const int bid  = blockIdx.x;      // 0..255
    const int xcd  = bid & 7;
    const int slot = bid >> 3;        // 0..31
    const int xm   = xcd >> 1;        // 0..3
    const int xn   = xcd & 1;         // 0..1
    const int mb   = xm * 4 + (slot & 3);   // 0..15 -> b in [mb*128, ...)
    const int nb   = xn * 8 + (slot >> 2);  // 0..15 -> d in [nb*32, ...)

    const int r  = lane & 15, q = lane >> 4;
    const int lr  = lane >> 3;        // row-in-8 for the staging loads
    const int lcs = ((lane & 7) ^ lr) * 8;            // swizzled SOURCE k-chunk
    const int ko  = (((wk << 2) + q) ^ (r & 7)) << 3; // swizzled read col (elems)

    f32x4 acc[4][4];
#pragma unroll
    for (int mi = 0; mi < 4; ++mi)
#pragma unroll
        for (int ni = 0; ni < 4; ++ni) {
            f32x4 z = {0.f, 0.f, 0.f, 0.f};
            acc[mi][ni] = z;
        }

    // stage K-step kt into buffer dst (4 gload16 per thread = 32 KiB/block)
    auto stage = [&](int dst, int kt) {
        const bf16_t* abase = (kt < 8) ? X0 : Hin;
        const int k0 = (kt & 7) * 64;
#pragma unroll
        for (int iss = 0; iss < 2; ++iss) {
            const int r0 = wid * 16 + iss * 8;       // r0 % 8 == 0
            gload16(abase + (size_t)(mb * 128 + r0 + lr) * 512 + k0 + lcs,
                    &As[dst][r0][0]);
        }
#pragma unroll
        for (int iss = 0; iss < 2; ++iss) {
            const int r0   = wid * 16 + iss * 8;
            const int nloc = r0 + lr;
            const int j    = (nloc >> 5) * 512 + nb * 32 + (nloc & 31);
            gload16(Wcat + (size_t)j * 1024 + kt * 64 + lcs,
                    &Bs[dst][r0][0]);
        }
    };

    // prologue: buffers 0,1 in flight (8 loads/thread)
    stage(0, 0);
    stage(1, 1);

#pragma unroll
    for (int kt = 0; kt < 16; ++kt) {
        if (kt + 2 < 16) stage((kt + 2) & 3, kt + 2);
        if (kt < 14) {
            asm volatile("s_waitcnt vmcnt(8)" ::: "memory");
        } else if (kt == 14) {
            asm volatile("s_waitcnt vmcnt(4)" ::: "memory");
        } else {
            asm volatile("s_waitcnt vmcnt(0)" ::: "memory");
        }
        __builtin_amdgcn_s_barrier();
        __builtin_amdgcn_sched_barrier(0);

        const int cur = kt & 3;
        bf16x8 af[4], bfr[4];
#pragma unroll
        for (int mi = 0; mi < 4; ++mi)
            af[mi] = *(const bf16x8*)&As[cur][wm * 64 + mi * 16 + r][ko];
#pragma unroll
        for (int ni = 0; ni < 4; ++ni)
            bfr[ni] = *(const bf16x8*)&Bs[cur][wn * 64 + ni * 16 + r][ko];
#pragma unroll
        for (int mi = 0; mi < 4; ++mi)
#pragma unroll
            for (int ni = 0; ni < 4; ++ni)
                acc[mi][ni] = __builtin_amdgcn_mfma_f32_16x16x32_bf16(
                    af[mi], bfr[ni], acc[mi][ni], 0, 0, 0);
    }

    // ---- epilogue ----
    const int row    = tid >> 2;          // 0..127
    const int dq     = (tid & 3) * 8;     // 0..24 (8 d's per thread)
    const int b_glob = mb * 128 + row;

    // prefetch cell state + W_out (latency hides under the Gs phase)
    float cv[8], wo[8];
    *(float4*)&cv[0] = *(const float4*)&Cbuf[(size_t)b_glob * 512 + nb * 32 + dq];
    *(float4*)&cv[4] = *(const float4*)&Cbuf[(size_t)b_glob * 512 + nb * 32 + dq + 4];
    *(float4*)&wo[0] = *(const float4*)&W_out[nb * 32 + dq];
    *(float4*)&wo[4] = *(const float4*)&W_out[nb * 32 + dq + 4];

    __syncthreads();   // all MFMA reads done -> overlay Gs on staging LDS

    // both k-halves store in parallel; XOR col-swizzle kills bank conflicts
    {
        float (*G)[128] = wk ? Gs1 : Gs0;
#pragma unroll
        for (int mi = 0; mi < 4; ++mi)
#pragma unroll
            for (int ni = 0; ni < 4; ++ni)
#pragma unroll
                for (int rr = 0; rr < 4; ++rr) {
                    const int gr = wm * 64 + mi * 16 + q * 4 + rr;
                    const int gc = wn * 64 + ni * 16 + r;
                    G[gr][gc ^ ((gr & 7) << 2)] = acc[mi][ni][rr];
                }
    }
    __syncthreads();

    {
        const int sx = (row & 7) << 2;
        float cnew[8];
        bf16_t hv[8];
        float yp = 0.f;
#pragma unroll
        for (int ii = 0; ii < 8; ++ii) {
            const int dl     = dq + ii;         // 0..31
            const int d_glob = nb * 32 + dl;
            const int c0x = (dl)      ^ sx;
            const int c1x = (32 + dl) ^ sx;
            const int c2x = (64 + dl) ^ sx;
            const int c3x = (96 + dl) ^ sx;
            float gi = Gs0[row][c0x] + Gs1[row][c0x] + b_gate[d_glob];
            float gf = Gs0[row][c1x] + Gs1[row][c1x] + b_gate[512  + d_glob];
            float gg = Gs0[row][c2x] + Gs1[row][c2x] + b_gate[1024 + d_glob];
            float go = Gs0[row][c3x] + Gs1[row][c3x] + b_gate[1536 + d_glob];
            float is = sigmoid_f(gi);
            float fs = sigmoid_f(gf);
            float os = sigmoid_f(go);
            float gt = tanh_f(gg);
            float c_new = fs * cv[ii] + is * gt;
            float hval  = os * tanh_f(c_new);
            cnew[ii] = c_new;
            hv[ii]   = (bf16_t)hval;
            yp += hval * wo[ii];
        }
        const size_t base = (size_t)b_glob * 512 + nb * 32 + dq;
        *(float4*)&Cbuf[base]     = *(const float4*)&cnew[0];
        *(float4*)&Cbuf[base + 4] = *(const float4*)&cnew[4];
        *(bf16x8*)&Hout[base]     = *(const bf16x8*)&hv[0];

        yp += __shfl_xor(yp, 1);
        yp += __shfl_xor(yp, 2);
        if ((tid & 3) == 0) atomicAdd(&yout[b_glob], yp);
    }
}

// ---------------------------------------------------------------------------
extern "C" void kernel_launch(void* const* d_in, const int* in_sizes, int n_in,
                              void* d_out, int out_size, void* d_ws, size_t ws_size,
                              hipStream_t stream) {
    const float* x     = (const float*)d_in[0];
    const float* h0    = (const float*)d_in[1];
    const float* c0    = (const float*)d_in[2];
    const float* y0    = (const float*)d_in[3];
    const float* W_in  = (const float*)d_in[4];
    const float* b_in  = (const float*)d_in[5];
    const float* W_ih  = (const float*)d_in[6];
    const float* W_hh  = (const float*)d_in[7];
    const float* b_ih  = (const float*)d_in[8];
    const float* b_hh  = (const float*)d_in[9];
    const float* W_out = (const float*)d_in[10];
    const float* b_out = (const float*)d_in[11];
    float* out = (float*)d_out;

    char* ws = (char*)d_ws;
    bf16_t* Wcat  = (bf16_t*)(ws);                 // 4 MiB  [2048][1024] bf16
    bf16_t* X0    = (bf16_t*)(ws + (4u << 20));    // 2 MiB  [2048][512]  bf16
    bf16_t* Hb0   = (bf16_t*)(ws + (6u << 20));    // 2 MiB
    bf16_t* Hb1   = (bf16_t*)(ws + (8u << 20));    // 2 MiB
    float*  Cbuf  = (float*)(ws + (10u << 20));    // 4 MiB  [2048][512]  f32
    float*  bgate = (float*)(ws + (14u << 20));    // 8 KiB  [2048]       f32
    bf16_t* Hb[2] = { Hb0, Hb1 };

    prep_w    <<<2048, 256, 0, stream>>>(W_ih, W_hh, Wcat);
    prep_state<<<2048, 256, 0, stream>>>(h0, c0, Hb[0], Cbuf);
    prep_bias <<<8,    256, 0, stream>>>(b_ih, b_hh, bgate);

    for (int t = 0; t < SEQ; ++t) {
        const float* yprev = (t == 0) ? y0 : (out + (size_t)(t - 1) * BATCH);
        input_proj<<<256, 256, 0, stream>>>(
            x + (size_t)t * BATCH * XF, yprev, W_in, b_in, b_out,
            X0, out + (size_t)t * BATCH);
        step_gemm_cell<<<256, 512, 0, stream>>>(
            X0, Hb[t & 1], Hb[(t + 1) & 1], Cbuf, Wcat, bgate, W_out,
            out + (size_t)t * BATCH);
    }
    (void)in_sizes; (void)n_in; (void)out_size; (void)ws_size;
}